// Round 7
// baseline (18806.450 us; speedup 1.0000x reference)
//
#include <hip/hip_runtime.h>
#include <cstdint>
#include <cstddef>

static constexpr int BS  = 128;
static constexpr int RAL = 1024;
static constexpr int LAL = 256;
static constexpr int CS  = 256;
static constexpr int VOC = 34;
static constexpr int HFS = 512;
static constexpr int EMB = 256;

static constexpr int NSPLIT = 2;
static constexpr int RSPL   = RAL / NSPLIT;   // 512 max rows per split block
static constexpr int NBLK   = 256;            // proven co-resident

typedef float  f32x4  __attribute__((ext_vector_type(4)));
typedef short  bf16x8 __attribute__((ext_vector_type(8)));

#define SC_AGENT __HIP_MEMORY_SCOPE_AGENT

static __device__ __forceinline__ float bflo(unsigned int u) {
    return __builtin_bit_cast(float, u << 16);
}
static __device__ __forceinline__ float bfhi(unsigned int u) {
    return __builtin_bit_cast(float, u & 0xffff0000u);
}
static __device__ __forceinline__ unsigned short f2bf(float f) {
    unsigned int x = __builtin_bit_cast(unsigned int, f);
    x = (x + 0x7fffu + ((x >> 16) & 1u)) >> 16;   // RNE
    return (unsigned short)x;
}
static __device__ __forceinline__ float bcf(unsigned u) { return __builtin_bit_cast(float, u); }
static __device__ __forceinline__ unsigned fcb(float f) { return __builtin_bit_cast(unsigned, f); }
static __device__ __forceinline__ float sigf(float x)   { return 1.0f / (1.0f + __expf(-x)); }
static __device__ __forceinline__ float tanhf_(float x) { return 1.0f - 2.0f / (__expf(2.0f * x) + 1.0f); }

// ---- agent-scope (device-coherent) accessors ----
static __device__ __forceinline__ unsigned ldu32(const void* p) {
    return __hip_atomic_load((const unsigned*)p, __ATOMIC_RELAXED, SC_AGENT);
}
static __device__ __forceinline__ unsigned long long ldu64(const void* p) {
    return __hip_atomic_load((const unsigned long long*)p, __ATOMIC_RELAXED, SC_AGENT);
}
static __device__ __forceinline__ void stu32(void* p, unsigned v) {
    __hip_atomic_store((unsigned*)p, v, __ATOMIC_RELAXED, SC_AGENT);
}
static __device__ __forceinline__ void stu64(void* p, unsigned long long v) {
    __hip_atomic_store((unsigned long long*)p, v, __ATOMIC_RELAXED, SC_AGENT);
}
static __device__ __forceinline__ bf16x8 ld_bf16x8_sys(const unsigned short* p) {
    union { unsigned long long q[2]; bf16x8 v; } u;
    u.q[0] = ldu64(p);
    u.q[1] = ldu64(p + 4);
    return u.v;
}
static __device__ __forceinline__ unsigned long long packbf4(float a, float b, float c, float d) {
    return (unsigned long long)f2bf(a)
         | ((unsigned long long)f2bf(b) << 16)
         | ((unsigned long long)f2bf(c) << 32)
         | ((unsigned long long)f2bf(d) << 48);
}
// int8 unpack helpers
static __device__ __forceinline__ float i8f(unsigned w) {
    return (float)(signed char)(w & 0xffu);
}
static __device__ __forceinline__ float dot4i8(unsigned w, const float* q) {
    return i8f(w) * q[0] + i8f(w >> 8) * q[1] + i8f(w >> 16) * q[2] + i8f(w >> 24) * q[3];
}

// ---------------- fp32 -> bf16 conversion (once per launch, weights only) ----------------
__global__ void cvt4_kernel(const float4* __restrict__ in, ushort4* __restrict__ out, int n4) {
    int i  = blockIdx.x * blockDim.x + threadIdx.x;
    int st = gridDim.x * blockDim.x;
    for (; i < n4; i += st) {
        float4 v = in[i];
        ushort4 o;
        o.x = f2bf(v.x); o.y = f2bf(v.y); o.z = f2bf(v.z); o.w = f2bf(v.w);
        out[i] = o;
    }
}

// ---------------- fp32 -> int8 per-row quantization (once per launch, KV) ----------------
__global__ __launch_bounds__(256) void quant8_kernel(const float* __restrict__ in,
                                                     signed char* __restrict__ out,
                                                     float* __restrict__ scale, int nrows) {
    const int row  = blockIdx.x * 4 + (threadIdx.x >> 6);
    const int lane = threadIdx.x & 63;
    if (row >= nrows) return;
    const float* rp = in + (long)row * CS;
    float4 v = *(const float4*)(rp + lane * 4);
    float m = fmaxf(fmaxf(fabsf(v.x), fabsf(v.y)), fmaxf(fabsf(v.z), fabsf(v.w)));
#pragma unroll
    for (int s = 32; s > 0; s >>= 1) m = fmaxf(m, __shfl_xor(m, s));
    const float inv = (m > 0.0f) ? 127.0f / m : 0.0f;
    unsigned a = (unsigned)((int)rintf(v.x * inv)) & 0xffu;
    unsigned b = (unsigned)((int)rintf(v.y * inv)) & 0xffu;
    unsigned c = (unsigned)((int)rintf(v.z * inv)) & 0xffu;
    unsigned d = (unsigned)((int)rintf(v.w * inv)) & 0xffu;
    *(unsigned*)(out + (long)row * CS + lane * 4) = a | (b << 8) | (c << 16) | (d << 24);
    if (lane == 0) scale[row] = (m > 0.0f) ? m / 127.0f : 0.0f;
}

// ---------------- valid-length precompute + attS init ----------------
__global__ __launch_bounds__(256) void len_kernel(const float* __restrict__ mask,
                                                  int* __restrict__ Llen,
                                                  float* __restrict__ attS) {
    __shared__ int red[256];
    const int b = blockIdx.x, tid = threadIdx.x;
    int c = 0;
    for (int r = tid; r < RAL; r += 256) c += (mask[b * RAL + r] != 0.0f) ? 1 : 0;
    red[tid] = c;
    __syncthreads();
    for (int s = 128; s > 0; s >>= 1) {
        if (tid < s) red[tid] += red[tid + s];
        __syncthreads();
    }
    if (tid == 0) Llen[b] = red[0];
    if (tid < NSPLIT) attS[b * NSPLIT + tid] = 1.0f / NSPLIT;  // attM=0, attC=0 -> ctx=0 at t=0
}

// ---------------- shared-memory overlays ----------------
struct SmLstm {
    float zp[7][4][64][4];   // 28672 B
    float hT[16][17];        //  1088 B  (epilogue transpose for packed h stores)
};
struct SmAttn {
    float hb_l[HFS + 8];    //  skewed: idx = i + (i>>7)
    float q_lds[CS + 8];    //  skewed: idx = c + (c>>6)
    float e_lds[RSPL];      //  2048
    float ctxp[64][CS + 4]; //  66560 (row pad kills write conflicts)
    float red[32];
};
static constexpr size_t SMSZ = sizeof(SmLstm) > sizeof(SmAttn) ? sizeof(SmLstm) : sizeof(SmAttn);

struct PParams {
    const void* keyp; const void* valp;          // int8 (KVQ) or f32
    const float* kscale; const float* vscale;    // per-row scales (KVQ)
    const int* Llen; const int* y;
    const unsigned short* embb;
    const unsigned short* WihA; const unsigned short* WhhA;
    const float* bihA; const float* bhhA;
    const unsigned short* WihB; const unsigned short* WhhB;
    const float* bihB; const float* bhhB;
    const unsigned short* Wqb; const float* bq;
    const float* Wc; const float* bc;
    unsigned short* ha; unsigned short* hbuf;
    float* ca; float* cbuf;
    float* attM; float* attS; float* attC;
    unsigned* grp; unsigned* root;
    float* outp;
};

// ---------------- hierarchical monotonic grid barrier (256 blocks = 16 groups x 16) ----
static __device__ __forceinline__ void gbar(unsigned* grp, unsigned* root, int blk, int round) {
    asm volatile("s_waitcnt vmcnt(0) lgkmcnt(0)" ::: "memory");
    __syncthreads();
    if (threadIdx.x == 0) {
        unsigned* g = grp + (blk >> 4) * 32;            // 16 groups, 128B-padded lines
        unsigned old = __hip_atomic_fetch_add(g, 1u, __ATOMIC_RELAXED, SC_AGENT);
        if (old == (unsigned)(round * 16 + 15))         // last of the group this round
            __hip_atomic_fetch_add(root, 1u, __ATOMIC_RELAXED, SC_AGENT);
        const unsigned tgt = (unsigned)((round + 1) * 16);
        while (__hip_atomic_load(root, __ATOMIC_RELAXED, SC_AGENT) < tgt)
            __builtin_amdgcn_s_sleep(2);
    }
    __syncthreads();
}

// ---------------- ctx merge: 8 bf16 elems from NSPLIT unnormalized partials ----------------
static __device__ __forceinline__ bf16x8 ctx_merge8(const float* cb, const float* wm) {
    union { unsigned short s[8]; bf16x8 v; } r;
#pragma unroll
    for (int e = 0; e < 8; e += 2) {
        float x0 = 0.f, x1 = 0.f;
#pragma unroll
        for (int s2 = 0; s2 < NSPLIT; ++s2) {
            unsigned long long q = ldu64(cb + (long)s2 * CS + e);
            x0 += wm[s2] * bcf((unsigned)q);
            x1 += wm[s2] * bcf((unsigned)(q >> 32));
        }
        r.s[e]     = f2bf(x0);
        r.s[e + 1] = f2bf(x1);
    }
    return r.v;
}

// ---------------- LSTM phase: waves 0-7 active (K-split 128 wide each) ----------------
// All 16 waves of the block MUST call this (unconditional internal __syncthreads).
template <bool ISA>
static __device__ __forceinline__ void lstm_phase(
    int blk, int tid,
    const unsigned short* xrow,            // !ISA: haOut base (stride HFS)
    const float* attM, const float* attS, const float* attC,   // ISA only
    const unsigned short* embb, const int* yidx, int t,        // ISA only
    const unsigned short* hIn,             // h-state base (stride HFS), coherent
    const unsigned short* Wih, const unsigned short* Whh,
    const float* bih, const float* bhh,
    float* cst, unsigned short* hout,
    SmLstm* sm)
{
    const int lane = tid & 63;
    const int wv   = tid >> 6;      // 0..15
    const bool act = (wv < 8);
    const int quad = lane >> 4;
    const int l16  = lane & 15;
    const int jsl  = blk & 31;
    const int bgr  = blk >> 5;
    const int j    = jsl * 16 + l16;
    const int mrow = bgr * 16 + l16;

    f32x4 acc[4];
#pragma unroll
    for (int g = 0; g < 4; ++g) acc[g] = (f32x4)0.0f;

    if (act) {
        const int seg  = wv >> 1;       // 0..3
        const int sub  = wv & 1;
        const int off0 = sub * 128 + quad * 8;

        const unsigned short* arow = nullptr;
        const float* c0 = nullptr;
        float wm[NSPLIT];
        bool scA;
        if (seg >= 2) {            // h-state
            arow = hIn + (long)mrow * HFS + (seg & 1) * 256 + off0;
            scA = true;
        } else if (!ISA) {         // x = haOut row
            arow = xrow + (long)mrow * HFS + (seg & 1) * 256 + off0;
            scA = true;
        } else if (seg == 0) {     // emb gather (plain, read-only)
            arow = embb + (long)yidx[mrow * LAL + t] * EMB + off0;
            scA = false;
        } else {                   // ctx merge (NSPLIT partials)
            c0 = attC + (long)mrow * NSPLIT * CS + off0;
            float Ms[NSPLIT], Ss[NSPLIT];
#pragma unroll
            for (int s = 0; s < NSPLIT; ++s) {
                Ms[s] = bcf(ldu32(attM + mrow * NSPLIT + s));
                Ss[s] = bcf(ldu32(attS + mrow * NSPLIT + s));
            }
            float mm = Ms[0];
#pragma unroll
            for (int s = 1; s < NSPLIT; ++s) mm = fmaxf(mm, Ms[s]);
            float den = 0.f;
#pragma unroll
            for (int s = 0; s < NSPLIT; ++s) { wm[s] = __expf(Ms[s] - mm); den += wm[s] * Ss[s]; }
            float inv = 1.0f / den;
#pragma unroll
            for (int s = 0; s < NSPLIT; ++s) wm[s] *= inv;
            scA = false;
        }

        const unsigned short* wb = ((seg < 2) ? Wih : Whh) + (seg & 1) * 256 + off0;
        const unsigned short* wg[4];
#pragma unroll
        for (int g = 0; g < 4; ++g) wg[g] = wb + (long)(g * HFS + j) * HFS;

#pragma unroll
        for (int kc = 0; kc < 4; ++kc) {
            bf16x8 a;
            if (scA)                   a = ld_bf16x8_sys(arow + kc * 32);
            else if (!ISA || seg == 0) a = *(const bf16x8*)(arow + kc * 32);
            else                       a = ctx_merge8(c0 + kc * 32, wm);
            bf16x8 b0 = *(const bf16x8*)(wg[0] + kc * 32);
            bf16x8 b1 = *(const bf16x8*)(wg[1] + kc * 32);
            bf16x8 b2 = *(const bf16x8*)(wg[2] + kc * 32);
            bf16x8 b3 = *(const bf16x8*)(wg[3] + kc * 32);
            acc[0] = __builtin_amdgcn_mfma_f32_16x16x32_bf16(a, b0, acc[0], 0, 0, 0);
            acc[1] = __builtin_amdgcn_mfma_f32_16x16x32_bf16(a, b1, acc[1], 0, 0, 0);
            acc[2] = __builtin_amdgcn_mfma_f32_16x16x32_bf16(a, b2, acc[2], 0, 0, 0);
            acc[3] = __builtin_amdgcn_mfma_f32_16x16x32_bf16(a, b3, acc[3], 0, 0, 0);
        }

        if (wv != 0) {
#pragma unroll
            for (int g = 0; g < 4; ++g)
                *(f32x4*)&sm->zp[wv - 1][g][lane][0] = acc[g];
        }
    }
    __syncthreads();   // ALL 16 waves
    if (wv == 0) {
#pragma unroll
        for (int g = 0; g < 4; ++g) {
#pragma unroll
            for (int w = 0; w < 7; ++w)
                acc[g] += *(const f32x4*)&sm->zp[w][g][lane][0];
        }
        const float bI = bih[j]           + bhh[j];
        const float bF = bih[HFS + j]     + bhh[HFS + j];
        const float bG = bih[2 * HFS + j] + bhh[2 * HFS + j];
        const float bO = bih[3 * HFS + j] + bhh[3 * HFS + j];
#pragma unroll
        for (int r = 0; r < 4; ++r) {
            int m   = bgr * 16 + quad * 4 + r;  // C/D row = batch
            int idx = m * HFS + j;
            float iv = sigf(acc[0][r] + bI);
            float fv = sigf(acc[1][r] + bF);
            float gv = tanhf_(acc[2][r] + bG);
            float ov = sigf(acc[3][r] + bO);
            float cn = fv * cst[idx] + iv * gv;
            cst[idx] = cn;
            sm->hT[quad * 4 + r][l16] = ov * tanhf_(cn);
        }
        // transpose & coherent-store packed h (4 bf16 per lane); wave-internal LDS RAW
        float h0 = sm->hT[l16][quad * 4 + 0];
        float h1 = sm->hT[l16][quad * 4 + 1];
        float h2 = sm->hT[l16][quad * 4 + 2];
        float h3 = sm->hT[l16][quad * 4 + 3];
        stu64(hout + (long)(bgr * 16 + l16) * HFS + jsl * 16 + quad * 4,
              packbf4(h0, h1, h2, h3));
    }
}

// ---------------- attention phase (block = (b, sp), all 1024 threads) ----------------
// KVQ: key/val int8 with per-row scales. Rebuilt for MLP: 16B loads, deep batches.
template <bool KVQ>
static __device__ __forceinline__ void attn_phase(
    int blk, int tid,
    const void* keyp, const void* valp,
    const float* __restrict__ kscale, const float* __restrict__ vscale,
    const int* __restrict__ Llen,
    const unsigned short* __restrict__ hbv,
    const unsigned short* __restrict__ Wqb, const float* __restrict__ bq,
    float* __restrict__ attM, float* __restrict__ attS, float* __restrict__ attC,
    SmAttn* sm)
{
    const int b     = blk >> 1;
    const int sp    = blk & 1;
    const int L     = Llen[b];
    const int rhalf = (L + 1) >> 1;               // balanced split boundary
    const int rbase = sp * rhalf;
    int nv = L - rbase;
    if (nv > rhalf) nv = rhalf;
    // L in [512,1024] -> nv in [256,512] always

    if (tid < 128) {   // coherent-load hb row, 4 bf16 per thread (skewed store)
        unsigned long long q = ldu64(hbv + (long)b * HFS + tid * 4);
        const int base = tid * 4 + (tid >> 5);     // skew: +1 per 128 elems
        sm->hb_l[base + 0] = bflo((unsigned)( q        & 0xffffu));
        sm->hb_l[base + 1] = bflo((unsigned)((q >> 16) & 0xffffu));
        sm->hb_l[base + 2] = bflo((unsigned)((q >> 32) & 0xffffu));
        sm->hb_l[base + 3] = bflo((unsigned)((q >> 48) & 0xffffu));
    }
    __syncthreads();

    // query: 4 threads per output col, 128-wide K chunks (Wq is L2-hot)
    {
        const int c  = tid >> 2;
        const int jj = tid & 3;
        const unsigned short* wr = Wqb + (long)c * HFS + jj * 128;
        const float* xr = &sm->hb_l[jj * 129];     // skewed segment base
        float qa = 0.0f;
#pragma unroll
        for (int k = 0; k < 128; k += 8) {
            uint4 u = *(const uint4*)(wr + k);
            float4 h0 = *(const float4*)(xr + k);
            float4 h1 = *(const float4*)(xr + k + 4);
            qa += bflo(u.x) * h0.x + bfhi(u.x) * h0.y
                + bflo(u.y) * h0.z + bfhi(u.y) * h0.w
                + bflo(u.z) * h1.x + bfhi(u.z) * h1.y
                + bflo(u.w) * h1.z + bfhi(u.w) * h1.w;
        }
        qa += __shfl_xor(qa, 1);
        qa += __shfl_xor(qa, 2);
        if (jj == 0) sm->q_lds[c + (c >> 6)] = qa + bq[c];   // skewed store
    }
    __syncthreads();

    // energy: 4 threads per row, BOTH candidate rows concurrently (8 loads in flight)
    {
        const int jj   = tid & 3;
        const int rloc = tid >> 2;        // 0..255
        const int rA = rloc, rB = rloc + 256;
        const bool vB = rB < nv;          // rA < nv always (nv >= 256)
        float accA = 0.0f, accB = 0.0f;
        if (KVQ) {
            const signed char* kb = (const signed char*)keyp
                + ((long)b * RAL + rbase) * CS + jj * 64;
            uint4 uA[4], uB[4];
#pragma unroll
            for (int i = 0; i < 4; ++i) uA[i] = *(const uint4*)(kb + (long)rA * CS + i * 16);
            if (vB) {
#pragma unroll
                for (int i = 0; i < 4; ++i) uB[i] = *(const uint4*)(kb + (long)rB * CS + i * 16);
            }
#pragma unroll
            for (int i = 0; i < 4; ++i) {
                const float* qp = &sm->q_lds[jj * 65 + i * 16];
                accA += dot4i8(uA[i].x, qp)     + dot4i8(uA[i].y, qp + 4)
                      + dot4i8(uA[i].z, qp + 8) + dot4i8(uA[i].w, qp + 12);
                if (vB)
                    accB += dot4i8(uB[i].x, qp)     + dot4i8(uB[i].y, qp + 4)
                          + dot4i8(uB[i].z, qp + 8) + dot4i8(uB[i].w, qp + 12);
            }
        } else {
            const float* kb = (const float*)keyp + ((long)b * RAL + rbase) * CS + jj * 64;
#pragma unroll
            for (int i = 0; i < 16; ++i) {
                float4 kv = *(const float4*)(kb + (long)rA * CS + i * 4);
                float4 qa = *(const float4*)&sm->q_lds[jj * 65 + i * 4];
                accA += kv.x * qa.x + kv.y * qa.y + kv.z * qa.z + kv.w * qa.w;
            }
            if (vB) {
#pragma unroll
                for (int i = 0; i < 16; ++i) {
                    float4 kv = *(const float4*)(kb + (long)rB * CS + i * 4);
                    float4 qa = *(const float4*)&sm->q_lds[jj * 65 + i * 4];
                    accB += kv.x * qa.x + kv.y * qa.y + kv.z * qa.z + kv.w * qa.w;
                }
            }
        }
        accA += __shfl_xor(accA, 1);  accA += __shfl_xor(accA, 2);
        accB += __shfl_xor(accB, 1);  accB += __shfl_xor(accB, 2);
        if (jj == 0) {
            if (KVQ) {
                sm->e_lds[rA] = accA * kscale[(long)b * RAL + rbase + rA];
                if (vB) sm->e_lds[rB] = accB * kscale[(long)b * RAL + rbase + rB];
            } else {
                sm->e_lds[rA] = accA;
                if (vB) sm->e_lds[rB] = accB;
            }
        }
    }
    __syncthreads();

    // local softmax stats (nv <= 512, one row per thread; 16-wave reduce)
    float pm = (tid < nv) ? sm->e_lds[tid] : -1e30f;
#pragma unroll
    for (int s = 32; s > 0; s >>= 1) pm = fmaxf(pm, __shfl_xor(pm, s));
    if ((tid & 63) == 0) sm->red[tid >> 6] = pm;
    __syncthreads();
    float M = sm->red[0];
#pragma unroll
    for (int i = 1; i < 16; ++i) M = fmaxf(M, sm->red[i]);

    float ps = 0.0f;
    if (tid < nv) {
        float v = __expf(sm->e_lds[tid] - M);
        ps = v;   // S accumulates UNSCALED exp
        sm->e_lds[tid] = KVQ ? v * vscale[(long)b * RAL + rbase + tid] : v;
    }
#pragma unroll
    for (int s = 32; s > 0; s >>= 1) ps += __shfl_xor(ps, s);
    if ((tid & 63) == 0) sm->red[16 + (tid >> 6)] = ps;
    __syncthreads();
    float S = 0.0f;
#pragma unroll
    for (int i = 0; i < 16; ++i) S += sm->red[16 + i];

    if (tid == 0) {
        stu32(attM + b * NSPLIT + sp, fcb(M));
        stu32(attS + b * NSPLIT + sp, fcb(S));
    }

    // partial context (unnormalized): 64 row-groups, lane owns 16 channels (16B int8 loads)
    {
        const int rg  = tid >> 4;          // 0..63
        const int c16 = (tid & 15) * 16;   // channel base
        float a[16];
#pragma unroll
        for (int i = 0; i < 16; ++i) a[i] = 0.0f;

        if (KVQ) {
            const signed char* vb = (const signed char*)valp
                + ((long)b * RAL + rbase) * CS + c16;
            int r = rg;
            for (; r + 192 < nv; r += 256) {       // 4-deep batches (<=2 total)
                uint4 u[4]; float w[4];
#pragma unroll
                for (int k = 0; k < 4; ++k) u[k] = *(const uint4*)(vb + (long)(r + 64 * k) * CS);
#pragma unroll
                for (int k = 0; k < 4; ++k) w[k] = sm->e_lds[r + 64 * k];
#pragma unroll
                for (int k = 0; k < 4; ++k) {
                    a[0]  += w[k] * i8f(u[k].x);       a[1]  += w[k] * i8f(u[k].x >> 8);
                    a[2]  += w[k] * i8f(u[k].x >> 16); a[3]  += w[k] * i8f(u[k].x >> 24);
                    a[4]  += w[k] * i8f(u[k].y);       a[5]  += w[k] * i8f(u[k].y >> 8);
                    a[6]  += w[k] * i8f(u[k].y >> 16); a[7]  += w[k] * i8f(u[k].y >> 24);
                    a[8]  += w[k] * i8f(u[k].z);       a[9]  += w[k] * i8f(u[k].z >> 8);
                    a[10] += w[k] * i8f(u[k].z >> 16); a[11] += w[k] * i8f(u[k].z >> 24);
                    a[12] += w[k] * i8f(u[k].w);       a[13] += w[k] * i8f(u[k].w >> 8);
                    a[14] += w[k] * i8f(u[k].w >> 16); a[15] += w[k] * i8f(u[k].w >> 24);
                }
            }
            for (; r < nv; r += 64) {
                uint4 u = *(const uint4*)(vb + (long)r * CS);
                float w = sm->e_lds[r];
                a[0]  += w * i8f(u.x);       a[1]  += w * i8f(u.x >> 8);
                a[2]  += w * i8f(u.x >> 16); a[3]  += w * i8f(u.x >> 24);
                a[4]  += w * i8f(u.y);       a[5]  += w * i8f(u.y >> 8);
                a[6]  += w * i8f(u.y >> 16); a[7]  += w * i8f(u.y >> 24);
                a[8]  += w * i8f(u.z);       a[9]  += w * i8f(u.z >> 8);
                a[10] += w * i8f(u.z >> 16); a[11] += w * i8f(u.z >> 24);
                a[12] += w * i8f(u.w);       a[13] += w * i8f(u.w >> 8);
                a[14] += w * i8f(u.w >> 16); a[15] += w * i8f(u.w >> 24);
            }
        } else {
            const float* vb = (const float*)valp + ((long)b * RAL + rbase) * CS + c16;
            for (int r = rg; r < nv; r += 64) {
                float w = sm->e_lds[r];
#pragma unroll
                for (int i = 0; i < 4; ++i) {
                    float4 v = *(const float4*)(vb + (long)r * CS + i * 4);
                    a[i * 4 + 0] += w * v.x; a[i * 4 + 1] += w * v.y;
                    a[i * 4 + 2] += w * v.z; a[i * 4 + 3] += w * v.w;
                }
            }
        }
#pragma unroll
        for (int i = 0; i < 4; ++i) {
            float4 o = {a[i * 4], a[i * 4 + 1], a[i * 4 + 2], a[i * 4 + 3]};
            *(float4*)&sm->ctxp[rg][c16 + i * 4] = o;
        }
    }
    __syncthreads();

    // 2-stage reduction: 64 rows -> 4 -> 1
    {
        const int g4 = tid >> 8;          // 0..3
        const int c  = tid & 255;
        float s4 = 0.0f;
#pragma unroll
        for (int k = 0; k < 16; ++k) s4 += sm->ctxp[g4 + 4 * k][c];
        __syncthreads();                  // all reads done before in-place writes visible? reads/writes same thread only; barrier for stage-2 ordering below
        sm->ctxp[g4][c] = s4;
    }
    __syncthreads();
    if (tid < CS) {
        float cv = sm->ctxp[0][tid] + sm->ctxp[1][tid] + sm->ctxp[2][tid] + sm->ctxp[3][tid];
        stu32(attC + ((long)b * NSPLIT + sp) * CS + tid, fcb(cv));   // unnormalized
    }
}

// ---------------- logits: 512-thread span; block = (16-batch, 1-2 vocab) slice ----------------
static __device__ __forceinline__ void logits_phase(
    int blk, int tid,   // tid in [0,512)
    const unsigned short* __restrict__ hb,
    const float* __restrict__ attM, const float* __restrict__ attS,
    const float* __restrict__ attC,
    const float* __restrict__ Wc, const float* __restrict__ bc,
    float* __restrict__ outp, int tOut)
{
    const int bgr  = blk >> 5;        // 0..7
    const int vsl  = blk & 31;        // 0..31
    const int bloc = tid >> 5;        // 0..15
    const int jj   = tid & 31;        // 0..31
    const int b    = bgr * 16 + bloc;

    float Ms[NSPLIT], Ss[NSPLIT], wgt[NSPLIT];
#pragma unroll
    for (int s = 0; s < NSPLIT; ++s) {
        Ms[s] = bcf(ldu32(attM + b * NSPLIT + s));
        Ss[s] = bcf(ldu32(attS + b * NSPLIT + s));
    }
    float mm = Ms[0];
#pragma unroll
    for (int s = 1; s < NSPLIT; ++s) mm = fmaxf(mm, Ms[s]);
    float den = 0.f;
#pragma unroll
    for (int s = 0; s < NSPLIT; ++s) { wgt[s] = __expf(Ms[s] - mm); den += wgt[s] * Ss[s]; }
    float inv = 1.0f / den;
#pragma unroll
    for (int s = 0; s < NSPLIT; ++s) wgt[s] *= inv;

    float xh[16];
    const unsigned short* hp = hb + (long)b * HFS + jj * 16;
#pragma unroll
    for (int g = 0; g < 4; ++g) {
        unsigned long long q = ldu64(hp + g * 4);
        xh[g * 4 + 0] = bflo((unsigned)( q        & 0xffffu));
        xh[g * 4 + 1] = bflo((unsigned)((q >> 16) & 0xffffu));
        xh[g * 4 + 2] = bflo((unsigned)((q >> 32) & 0xffffu));
        xh[g * 4 + 3] = bflo((unsigned)((q >> 48) & 0xffffu));
    }
    float xc[8];
    const float* cb = attC + (long)b * NSPLIT * CS + jj * 8;
#pragma unroll
    for (int g = 0; g < 4; ++g) {
        float x0 = 0.f, x1 = 0.f;
#pragma unroll
        for (int s = 0; s < NSPLIT; ++s) {
            unsigned long long q = ldu64(cb + (long)s * CS + g * 2);
            x0 += wgt[s] * bcf((unsigned)q);
            x1 += wgt[s] * bcf((unsigned)(q >> 32));
        }
        xc[g * 2]     = x0;
        xc[g * 2 + 1] = x1;
    }

#pragma unroll
    for (int vv = 0; vv < 2; ++vv) {
        int v = vsl + vv * 32;
        if (v >= VOC) break;
        const float* wr = Wc + (long)v * (HFS + CS);
        float part = 0.0f;
#pragma unroll
        for (int g = 0; g < 4; ++g) {
            float4 wv4 = *(const float4*)(wr + jj * 16 + g * 4);
            part += wv4.x * xh[g * 4 + 0] + wv4.y * xh[g * 4 + 1]
                  + wv4.z * xh[g * 4 + 2] + wv4.w * xh[g * 4 + 3];
        }
#pragma unroll
        for (int g = 0; g < 2; ++g) {
            float4 wv4 = *(const float4*)(wr + HFS + jj * 8 + g * 4);
            part += wv4.x * xc[g * 4 + 0] + wv4.y * xc[g * 4 + 1]
                  + wv4.z * xc[g * 4 + 2] + wv4.w * xc[g * 4 + 3];
        }
        part += __shfl_xor(part, 1);
        part += __shfl_xor(part, 2);
        part += __shfl_xor(part, 4);
        part += __shfl_xor(part, 8);
        part += __shfl_xor(part, 16);
        if (jj == 0)
            outp[((long)b * LAL + tOut) * VOC + v] = part + bc[v];
    }
}

// ---------------- fused kernel: 256 blocks x 1024 threads, 3 barriers/step ----------------
template <bool KVQ>
__global__ __launch_bounds__(1024, 4) void fused_kernel(PParams P)
{
    __shared__ __align__(16) unsigned char smraw[SMSZ];
    SmLstm* smL = (SmLstm*)smraw;
    SmAttn* smA = (SmAttn*)smraw;

    const int blk = blockIdx.x;
    const int tid = threadIdx.x;
    const int wv  = tid >> 6;
    int round = 0;

    for (int t = 0; t < LAL; ++t) {
        const unsigned short* haIn  = P.ha   + (t & 1) * (BS * HFS);
        unsigned short*       haOut = P.ha   + ((t + 1) & 1) * (BS * HFS);
        const unsigned short* hbIn  = P.hbuf + (t & 1) * (BS * HFS);
        unsigned short*       hbOut = P.hbuf + ((t + 1) & 1) * (BS * HFS);

        // phase 1: LSTM A (waves 0-7)
        lstm_phase<true>(blk, tid, nullptr, P.attM, P.attS, P.attC,
                         P.embb, P.y, t, haIn,
                         P.WihA, P.WhhA, P.bihA, P.bhhA, P.ca, haOut, smL);
        gbar(P.grp, P.root, blk, round++);

        // phase 2: LSTM B (waves 0-7) CONCURRENT with logits(t-1) (waves 8-15)
        if (wv >= 8 && t > 0)
            logits_phase(blk, tid - 512, hbIn, P.attM, P.attS, P.attC,
                         P.Wc, P.bc, P.outp, t - 1);
        lstm_phase<false>(blk, tid, haOut, nullptr, nullptr, nullptr,
                          nullptr, nullptr, t, hbIn,
                          P.WihB, P.WhhB, P.bihB, P.bhhB, P.cbuf, hbOut, smL);
        gbar(P.grp, P.root, blk, round++);

        // phase 3: attention partials (all 16 waves; in-block q)
        attn_phase<KVQ>(blk, tid, P.keyp, P.valp, P.kscale, P.vscale, P.Llen,
                        hbOut, P.Wqb, P.bq, P.attM, P.attS, P.attC, smA);
        gbar(P.grp, P.root, blk, round++);
    }
    // final logits (t = LAL-1); hb(LAL-1) lives in hbuf[LAL & 1] == hbuf[0]
    if (tid < 512)
        logits_phase(blk, tid, P.hbuf + (LAL & 1) * (BS * HFS),
                     P.attM, P.attS, P.attC, P.Wc, P.bc, P.outp, LAL - 1);
}

// ---------------- host ----------------
extern "C" void kernel_launch(void* const* d_in, const int* in_sizes, int n_in,
                              void* d_out, int out_size, void* d_ws, size_t ws_size,
                              hipStream_t stream)
{
    (void)in_sizes; (void)n_in; (void)out_size;
    const float* keyf  = (const float*)d_in[0];
    const float* valf  = (const float*)d_in[1];
    const float* mask  = (const float*)d_in[2];
    const float* embf  = (const float*)d_in[3];
    const float* WihAf = (const float*)d_in[4];
    const float* WhhAf = (const float*)d_in[5];
    const float* bihA  = (const float*)d_in[6];
    const float* bhhA  = (const float*)d_in[7];
    const float* WihBf = (const float*)d_in[8];
    const float* WhhBf = (const float*)d_in[9];
    const float* bihB  = (const float*)d_in[10];
    const float* bhhB  = (const float*)d_in[11];
    const float* Wqf   = (const float*)d_in[12];
    const float* bq    = (const float*)d_in[13];
    const float* Wc    = (const float*)d_in[14];
    const float* bc    = (const float*)d_in[15];
    const int*   y     = (const int*)d_in[16];
    float* outp = (float*)d_out;

    size_t off = 0;
    auto take = [&](size_t bytes) -> void* {
        void* p = (char*)d_ws + off;
        off += (bytes + 255) & ~(size_t)255;
        return p;
    };

    // ---- zero-initialized state block (memset every launch; includes barrier counters) ----
    unsigned short* ha    = (unsigned short*)take((size_t)2 * BS * HFS * 2); // double-buffered
    unsigned short* hbuf  = (unsigned short*)take((size_t)2 * BS * HFS * 2); // double-buffered
    float*          ca    = (float*)take((size_t)BS * HFS * 4);
    float*          cbuf  = (float*)take((size_t)BS * HFS * 4);
    float*          attM  = (float*)take((size_t)BS * NSPLIT * 4);
    float*          attS  = (float*)take((size_t)BS * NSPLIT * 4);
    float*          attC  = (float*)take((size_t)BS * NSPLIT * CS * 4);
    unsigned*       grp   = (unsigned*)take((size_t)16 * 32 * 4);   // padded group counters
    unsigned*       root  = (unsigned*)take((size_t)32 * 4);
    size_t stateBytes = off;

    int*            Llen  = (int*)take((size_t)BS * 4);
    unsigned short* embb  = (unsigned short*)take((size_t)VOC * EMB * 2);
    unsigned short* WihAb = (unsigned short*)take((size_t)4 * HFS * HFS * 2);
    unsigned short* WhhAb = (unsigned short*)take((size_t)4 * HFS * HFS * 2);
    unsigned short* WihBb = (unsigned short*)take((size_t)4 * HFS * HFS * 2);
    unsigned short* WhhBb = (unsigned short*)take((size_t)4 * HFS * HFS * 2);
    unsigned short* Wqb   = (unsigned short*)take((size_t)CS * HFS * 2);

    // --- int8 KV + per-row scales (f32 fallback if ws too small) ---
    const size_t q8Bytes = (size_t)BS * RAL * CS;        // 33.5 MB each
    const size_t scBytes = (size_t)BS * RAL * 4;         // 512 KB each
    signed char* key8 = nullptr;
    signed char* val8 = nullptr;
    float* kscale = nullptr;
    float* vscale = nullptr;
    bool kvq = false;
    if (off + 2 * (q8Bytes + 256) + 2 * (scBytes + 256) <= ws_size) {
        key8   = (signed char*)take(q8Bytes);
        val8   = (signed char*)take(q8Bytes);
        kscale = (float*)take(scBytes);
        vscale = (float*)take(scBytes);
        kvq = true;
    }

    hipMemsetAsync(d_ws, 0, stateBytes, stream);
    len_kernel<<<dim3(BS), dim3(256), 0, stream>>>(mask, Llen, attS);

    auto cvt = [&](const float* src, unsigned short* dst, long n) {
        int n4 = (int)(n / 4);
        int blocks = (n4 + 255) / 256;
        if (blocks > 8192) blocks = 8192;
        cvt4_kernel<<<dim3(blocks), dim3(256), 0, stream>>>((const float4*)src, (ushort4*)dst, n4);
    };
    cvt(embf,  embb,  (long)VOC * EMB);
    cvt(WihAf, WihAb, (long)4 * HFS * HFS);
    cvt(WhhAf, WhhAb, (long)4 * HFS * HFS);
    cvt(WihBf, WihBb, (long)4 * HFS * HFS);
    cvt(WhhBf, WhhBb, (long)4 * HFS * HFS);
    cvt(Wqf,   Wqb,   (long)CS * HFS);
    if (kvq) {
        const int nrows = BS * RAL;
        quant8_kernel<<<dim3(nrows / 4), dim3(256), 0, stream>>>(keyf, key8, kscale, nrows);
        quant8_kernel<<<dim3(nrows / 4), dim3(256), 0, stream>>>(valf, val8, vscale, nrows);
    }

    PParams prm;
    prm.keyp = kvq ? (const void*)key8 : (const void*)keyf;
    prm.valp = kvq ? (const void*)val8 : (const void*)valf;
    prm.kscale = kscale; prm.vscale = vscale;
    prm.Llen = Llen; prm.y = y;
    prm.embb = embb;
    prm.WihA = WihAb; prm.WhhA = WhhAb; prm.bihA = bihA; prm.bhhA = bhhA;
    prm.WihB = WihBb; prm.WhhB = WhhBb; prm.bihB = bihB; prm.bhhB = bhhB;
    prm.Wqb = Wqb; prm.bq = bq; prm.Wc = Wc; prm.bc = bc;
    prm.ha = ha; prm.hbuf = hbuf; prm.ca = ca; prm.cbuf = cbuf;
    prm.attM = attM; prm.attS = attS; prm.attC = attC;
    prm.grp = grp; prm.root = root;
    prm.outp = outp;

    void* kargs[] = { &prm };
    if (kvq)
        hipLaunchCooperativeKernel(reinterpret_cast<void*>(&fused_kernel<true>),
                                   dim3(NBLK), dim3(1024), kargs, 0, stream);
    else
        hipLaunchCooperativeKernel(reinterpret_cast<void*>(&fused_kernel<false>),
                                   dim3(NBLK), dim3(1024), kargs, 0, stream);
}